// Round 3
// baseline (17328.571 us; speedup 1.0000x reference)
//
#include <hip/hip_runtime.h>
#include <hip/hip_bf16.h>
#include <stdint.h>

#define TT 64
#define BB 512
#define XX 1024
#define HH 1024
#define ZZ 256
#define AA 64

#define NBLK 256
#define NTHR 512

typedef __bf16 bf16;
typedef bf16 bf16x8 __attribute__((ext_vector_type(8)));
typedef float f32x4 __attribute__((ext_vector_type(4)));

// d_out layout (fp32): beliefs[T+1,B,H] | q_loc | q_scale | p_loc | p_scale | z_q (each [T,B,Z])
#define SZ_BEL ((long)(TT + 1) * BB * HH)
#define SZ_TBZ ((long)TT * BB * ZZ)
#define OFF_QL (SZ_BEL)
#define OFF_QS (OFF_QL + SZ_TBZ)
#define OFF_PL (OFF_QL + 2 * SZ_TBZ)
#define OFF_PS (OFF_QL + 3 * SZ_TBZ)
#define OFF_ZQ (OFF_QL + 4 * SZ_TBZ)

#define GLL16(g, l)                                                         \
  __builtin_amdgcn_global_load_lds(                                         \
      (__attribute__((address_space(1))) void*)(g),                         \
      (__attribute__((address_space(3))) void*)(l), 16, 0, 0)

#define MFMA(a, b, c) __builtin_amdgcn_mfma_f32_16x16x32_bf16(a, b, c, 0, 0, 0)

__device__ __forceinline__ float eluf(float x) { return x > 0.f ? x : expf(x) - 1.f; }
__device__ __forceinline__ float splusf(float x) { return fmaxf(x, 0.f) + log1pf(expf(-fabsf(x))); }
__device__ __forceinline__ float sigf(float x) { return 1.f / (1.f + expf(-x)); }

// ---------------- persistent scan kernel ----------------

struct ScanArgs {
  const bf16 *WT_h, *WT_qh, *WT_ag, *WT_ih;
  const bf16 *obs_pre, *act_bf;
  bf16 *h_bf, *hid_q, *z_bf, *a_buf;
  float* gh;
  const float *b_q1, *b_ghh, *b_qm, *b_qs, *b_ag, *b_gih;
  const float* eps;
  float* dout;
  unsigned* bar;
};

// grid barrier: all 256 blocks co-resident by construction (48KB LDS, <=128 VGPR,
// 512 thr -> >=2 blocks/CU capacity, grid = 256 = 1/CU). Monotonic counter.
__device__ __forceinline__ void gsync(unsigned* bar, unsigned& gen) {
  __syncthreads();
  if (threadIdx.x == 0) {
    __threadfence();
    atomicAdd(bar, 1u);
    unsigned tgt = (++gen) * NBLK;
    while (__hip_atomic_load(bar, __ATOMIC_RELAXED, __HIP_MEMORY_SCOPE_AGENT) < tgt)
      __builtin_amdgcn_s_sleep(8);
  }
  __syncthreads();
  __threadfence();
}

// swizzled frag read: w = byte offset within 128-byte k-row (16B aligned)
__device__ __forceinline__ bf16x8 ldfrag(const bf16* buf, int row, int w) {
  return *(const bf16x8*)((const char*)buf + row * 128 + (w ^ ((row & 7) << 4)));
}

// stage nrows x 64 bf16 k-tile, linear LDS dest, inverse-swizzled global source
__device__ __forceinline__ void stage_rows(const bf16* base, long ld, int k0,
                                           char* lds, int nrows) {
  for (int c = threadIdx.x; c < nrows * 8; c += NTHR) {
    int row = c >> 3, cb = (c & 7) << 4;
    int scb = (cb ^ ((row & 7) << 4)) >> 1;
    GLL16(base + (long)row * ld + k0 + scb, lds + c * 16);
  }
}

__global__ __launch_bounds__(NTHR, 4) void scan_k(ScanArgs s) {
  __shared__ char smem[49152];
  bf16* sA = (bf16*)smem;              // 2 x 4096 elems (8KB each)
  bf16* sB = (bf16*)(smem + 16384);    // 2 x up-to-8192 elems (16KB each)
  const int bid = blockIdx.x, tid = threadIdx.x;
  const int wid = tid >> 6, lane = tid & 63;
  const int lr = lane & 15, lk = lane >> 4;
  unsigned gen = 0;

  for (int t = 0; t < TT; ++t) {
    // ---- P1: hid_q | gh = h @ [qW1_h | Whh]  (M=512,N=4096,K=1024), 256 blocks
    {
      const int m = bid >> 5, n = bid & 31;
      const int m0 = m * 64, n0 = n * 128;
      const int wm = wid & 1, wn = wid >> 1;
      const bf16* Ag = s.h_bf + (long)m0 * HH;
      const bf16* Bg = s.WT_h + (long)n0 * HH;
      f32x4 acc[2][2] = {};
      stage_rows(Ag, HH, 0, (char*)sA, 64);
      stage_rows(Bg, HH, 0, (char*)sB, 128);
      __syncthreads();
      for (int kt = 0; kt < 16; ++kt) {
        int cur = kt & 1;
        if (kt < 15) {
          stage_rows(Ag, HH, (kt + 1) * 64, (char*)(sA + (cur ^ 1) * 4096), 64);
          stage_rows(Bg, HH, (kt + 1) * 64, (char*)(sB + (cur ^ 1) * 8192), 128);
        }
        const bf16* Ab = sA + cur * 4096;
        const bf16* Bb = sB + cur * 8192;
#pragma unroll
        for (int ks = 0; ks < 2; ++ks) {
          int w = ks * 64 + lk * 16;
          bf16x8 a0 = ldfrag(Ab, wm * 32 + lr, w);
          bf16x8 a1 = ldfrag(Ab, wm * 32 + 16 + lr, w);
          bf16x8 b0 = ldfrag(Bb, wn * 32 + lr, w);
          bf16x8 b1 = ldfrag(Bb, wn * 32 + 16 + lr, w);
          acc[0][0] = MFMA(a0, b0, acc[0][0]);
          acc[0][1] = MFMA(a0, b1, acc[0][1]);
          acc[1][0] = MFMA(a1, b0, acc[1][0]);
          acc[1][1] = MFMA(a1, b1, acc[1][1]);
        }
        __syncthreads();
      }
#pragma unroll
      for (int mi = 0; mi < 2; mi++)
#pragma unroll
        for (int nj = 0; nj < 2; nj++)
#pragma unroll
          for (int r = 0; r < 4; r++) {
            int row = m0 + wm * 32 + mi * 16 + lk * 4 + r;
            int col = n0 + wn * 32 + nj * 16 + lr;
            float v = acc[mi][nj][r];
            if (n0 < HH) {
              float x = v + s.b_q1[col] + (float)s.obs_pre[((long)t * BB + row) * HH + col];
              s.hid_q[row * HH + col] = (bf16)eluf(x);
            } else {
              int j = col - HH;
              s.gh[(long)row * 3 * HH + j] = v + s.b_ghh[j];
            }
          }
    }
    gsync(s.bar, gen);

    // ---- P2: q-heads dual + rsample (M=512, Z=256 dual, K=1024), 32 blocks
    if (bid < 32) {
      const int m = bid >> 2, n = bid & 3;
      const int m0 = m * 64, n0 = n * 64;
      const int wm = wid & 1, wn = wid >> 1;
      const bf16* Ag = s.hid_q + (long)m0 * HH;
      f32x4 accL[2] = {}, accS[2] = {};
      stage_rows(Ag, HH, 0, (char*)sA, 64);
      for (int c = tid; c < 1024; c += NTHR) {
        int row = c >> 3, cb = (c & 7) << 4;
        int scb = (cb ^ ((row & 7) << 4)) >> 1;
        int brow = (row < 64) ? (n0 + row) : (192 + n0 + row);
        GLL16(s.WT_qh + (long)brow * HH + scb, (char*)sB + c * 16);
      }
      __syncthreads();
      for (int kt = 0; kt < 16; ++kt) {
        int cur = kt & 1;
        if (kt < 15) {
          stage_rows(Ag, HH, (kt + 1) * 64, (char*)(sA + (cur ^ 1) * 4096), 64);
          for (int c = tid; c < 1024; c += NTHR) {
            int row = c >> 3, cb = (c & 7) << 4;
            int scb = (cb ^ ((row & 7) << 4)) >> 1;
            int brow = (row < 64) ? (n0 + row) : (192 + n0 + row);
            GLL16(s.WT_qh + (long)brow * HH + (kt + 1) * 64 + scb,
                  (char*)(sB + (cur ^ 1) * 8192) + c * 16);
          }
        }
        const bf16* Ab = sA + cur * 4096;
        const bf16* Bb = sB + cur * 8192;
#pragma unroll
        for (int ks = 0; ks < 2; ++ks) {
          int w = ks * 64 + lk * 16;
          bf16x8 a0 = ldfrag(Ab, wm * 32 + lr, w);
          bf16x8 a1 = ldfrag(Ab, wm * 32 + 16 + lr, w);
          bf16x8 bl = ldfrag(Bb, wn * 16 + lr, w);
          bf16x8 bs = ldfrag(Bb, 64 + wn * 16 + lr, w);
          accL[0] = MFMA(a0, bl, accL[0]);
          accL[1] = MFMA(a1, bl, accL[1]);
          accS[0] = MFMA(a0, bs, accS[0]);
          accS[1] = MFMA(a1, bs, accS[1]);
        }
        __syncthreads();
      }
#pragma unroll
      for (int mi = 0; mi < 2; mi++)
#pragma unroll
        for (int r = 0; r < 4; r++) {
          int row = m0 + wm * 32 + mi * 16 + lk * 4 + r;
          int j = n0 + wn * 16 + lr;
          long o = ((long)t * BB + row) * ZZ + j;
          float loc = accL[mi][r] + s.b_qm[j];
          float sc = splusf(accS[mi][r] + s.b_qs[j]);
          float z = loc + sc * s.eps[o];
          s.dout[OFF_QL + o] = loc;
          s.dout[OFF_QS + o] = sc;
          s.dout[OFF_ZQ + o] = z;
          s.z_bf[row * ZZ + j] = (bf16)z;
        }
    }
    gsync(s.bar, gen);

    // ---- P3: a = elu([z|act] @ aggr_W + b)  (M=512,N=1024,K=320), 128 blocks
    if (bid < 128) {
      const int m = bid >> 4, n = bid & 15;
      const int m0 = m * 64, n0 = n * 64;
      const int wm = wid & 1, wn = wid >> 1;
      const bf16* Bg = s.WT_ag + (long)n0 * 320;
      f32x4 acc[2] = {};
      auto stageA3 = [&](int ktn, char* dst) {
        int c = tid;
        int row = c >> 3, cb = (c & 7) << 4;
        int scb = (cb ^ ((row & 7) << 4)) >> 1;
        const bf16* src = (ktn < 4)
            ? s.z_bf + (long)(m0 + row) * ZZ + ktn * 64 + scb
            : s.act_bf + (long)t * BB * AA + (long)(m0 + row) * AA + scb;
        GLL16(src, dst + c * 16);
      };
      stageA3(0, (char*)sA);
      stage_rows(Bg, 320, 0, (char*)sB, 64);
      __syncthreads();
      for (int kt = 0; kt < 5; ++kt) {
        int cur = kt & 1;
        if (kt < 4) {
          stageA3(kt + 1, (char*)(sA + (cur ^ 1) * 4096));
          stage_rows(Bg, 320, (kt + 1) * 64, (char*)(sB + (cur ^ 1) * 8192), 64);
        }
        const bf16* Ab = sA + cur * 4096;
        const bf16* Bb = sB + cur * 8192;
#pragma unroll
        for (int ks = 0; ks < 2; ++ks) {
          int w = ks * 64 + lk * 16;
          bf16x8 a0 = ldfrag(Ab, wm * 32 + lr, w);
          bf16x8 a1 = ldfrag(Ab, wm * 32 + 16 + lr, w);
          bf16x8 b = ldfrag(Bb, wn * 16 + lr, w);
          acc[0] = MFMA(a0, b, acc[0]);
          acc[1] = MFMA(a1, b, acc[1]);
        }
        __syncthreads();
      }
#pragma unroll
      for (int mi = 0; mi < 2; mi++)
#pragma unroll
        for (int r = 0; r < 4; r++) {
          int row = m0 + wm * 32 + mi * 16 + lk * 4 + r;
          int col = n0 + wn * 16 + lr;
          s.a_buf[row * HH + col] = (bf16)eluf(acc[mi][r] + s.b_ag[col]);
        }
    }
    gsync(s.bar, gen);

    // ---- P4: gi = a @ Wih + GRU gates  (M=512,N=3072,K=1024), 256 blocks
    {
      const int m = bid >> 5, jb = bid & 31;
      const int m0 = m * 64, j0 = jb * 32;
      const int wm4 = wid & 3, wn2 = wid >> 2;
      const bf16* Ag = s.a_buf + (long)m0 * HH;
      f32x4 acc[3] = {};
      auto stageB4 = [&](int k0, char* dst) {
        for (int c = tid; c < 768; c += NTHR) {
          int row = c >> 3, cb = (c & 7) << 4;
          int scb = (cb ^ ((row & 7) << 4)) >> 1;
          int brow = (row >> 5) * HH + j0 + (row & 31);
          GLL16(s.WT_ih + (long)brow * HH + k0 + scb, dst + c * 16);
        }
      };
      stage_rows(Ag, HH, 0, (char*)sA, 64);
      stageB4(0, (char*)sB);
      __syncthreads();
      for (int kt = 0; kt < 16; ++kt) {
        int cur = kt & 1;
        if (kt < 15) {
          stage_rows(Ag, HH, (kt + 1) * 64, (char*)(sA + (cur ^ 1) * 4096), 64);
          stageB4((kt + 1) * 64, (char*)(sB + (cur ^ 1) * 8192));
        }
        const bf16* Ab = sA + cur * 4096;
        const bf16* Bb = sB + cur * 8192;
#pragma unroll
        for (int ks = 0; ks < 2; ++ks) {
          int w = ks * 64 + lk * 16;
          bf16x8 a = ldfrag(Ab, wm4 * 16 + lr, w);
          bf16x8 b0 = ldfrag(Bb, wn2 * 16 + lr, w);
          bf16x8 b1 = ldfrag(Bb, 32 + wn2 * 16 + lr, w);
          bf16x8 b2 = ldfrag(Bb, 64 + wn2 * 16 + lr, w);
          acc[0] = MFMA(a, b0, acc[0]);
          acc[1] = MFMA(a, b1, acc[1]);
          acc[2] = MFMA(a, b2, acc[2]);
        }
        __syncthreads();
      }
#pragma unroll
      for (int r = 0; r < 4; r++) {
        int row = m0 + wm4 * 16 + lk * 4 + r;
        int j = j0 + wn2 * 16 + lr;
        long gb = (long)row * 3 * HH + j;
        float gir = acc[0][r] + s.b_gih[j] + s.gh[gb];
        float giz = acc[1][r] + s.b_gih[HH + j] + s.gh[gb + HH];
        float gin = acc[2][r] + s.b_gih[2 * HH + j];
        float rr = sigf(gir);
        float zz = sigf(giz);
        float nn = tanhf(gin + rr * s.gh[gb + 2 * HH]);
        float h = (float)s.h_bf[row * HH + j];
        float hn = (1.f - zz) * nn + zz * h;
        s.h_bf[row * HH + j] = (bf16)hn;
        s.dout[(long)(t + 1) * BB * HH + (long)row * HH + j] = hn;
      }
    }
    gsync(s.bar, gen);
  }
}

// ---------------- batched GEMMs (prep / tails), round-1 structure ----------------

struct GArgs {
  const bf16* A; const float* Af;
  long lda;
  const bf16* Bt;
  int M, N, K;
  const float *b_p1, *b_pm, *b_ps;
  bf16* out_bf;
  float* dout;
};

// EPI: 0 = store bf16 raw   5 = elu+bias -> bf16   6 = p-heads -> d_out
template <int BM, int BN, int EPI, bool AF32>
__global__ __launch_bounds__(256) void gemm_k(GArgs g) {
  constexpr int BK = 32;
  constexpr int WTM = BM / 2, WTN = BN / 2;
  constexpr int MR = WTM / 16, NR = WTN / 16;
  constexpr int CA = BM * 4 / 256, CB = BN * 4 / 256;
  __shared__ bf16 sA[BM * BK];
  __shared__ bf16 sB[BN * BK];
  const int nbm = g.M / BM;
  const int bm = blockIdx.x % nbm, bn = blockIdx.x / nbm;
  const int m0 = bm * BM, n0 = bn * BN;
  const int tid = threadIdx.x;
  const int wid = tid >> 6, lane = tid & 63;
  const int wm = wid & 1, wn = wid >> 1;
  const int lr = lane & 15, lk = lane >> 4;

  f32x4 acc[MR][NR] = {};

  for (int k0 = 0; k0 < g.K; k0 += BK) {
    __syncthreads();
    if constexpr (AF32) {
#pragma unroll
      for (int i = 0; i < CA; i++) {
        int c = tid + i * 256, row = c >> 2, kc = c & 3;
        const float* sp = g.Af + (long)(m0 + row) * g.lda + k0 + kc * 8;
        float4 v0 = *(const float4*)sp;
        float4 v1 = *(const float4*)(sp + 4);
        bf16x8 p;
        p[0] = (bf16)v0.x; p[1] = (bf16)v0.y; p[2] = (bf16)v0.z; p[3] = (bf16)v0.w;
        p[4] = (bf16)v1.x; p[5] = (bf16)v1.y; p[6] = (bf16)v1.z; p[7] = (bf16)v1.w;
        *(bf16x8*)&sA[c * 8] = p;
      }
    } else {
#pragma unroll
      for (int i = 0; i < CA; i++) {
        int c = tid + i * 256, row = c >> 2, kc = c & 3;
        GLL16(g.A + (long)(m0 + row) * g.lda + k0 + kc * 8, &sA[c * 8]);
      }
    }
#pragma unroll
    for (int i = 0; i < CB; i++) {
      int c = tid + i * 256, row = c >> 2, kc = c & 3;
      GLL16(g.Bt + (long)(n0 + row) * g.K + k0 + kc * 8, &sB[c * 8]);
    }
    __syncthreads();
    bf16x8 af[MR];
#pragma unroll
    for (int mi = 0; mi < MR; mi++)
      af[mi] = *(const bf16x8*)&sA[(wm * WTM + mi * 16 + lr) * BK + lk * 8];
#pragma unroll
    for (int nj = 0; nj < NR; nj++) {
      bf16x8 bfr = *(const bf16x8*)&sB[(wn * WTN + nj * 16 + lr) * BK + lk * 8];
#pragma unroll
      for (int mi = 0; mi < MR; mi++)
        acc[mi][nj] = MFMA(af[mi], bfr, acc[mi][nj]);
    }
  }

#pragma unroll
  for (int mi = 0; mi < MR; mi++)
#pragma unroll
    for (int nj = 0; nj < NR; nj++)
#pragma unroll
      for (int r = 0; r < 4; r++) {
        const int row = m0 + wm * WTM + mi * 16 + lk * 4 + r;
        const int col = n0 + wn * WTN + nj * 16 + lr;
        float v = acc[mi][nj][r];
        if constexpr (EPI == 0) {
          g.out_bf[(long)row * g.N + col] = (bf16)v;
        } else if constexpr (EPI == 5) {
          g.out_bf[(long)row * g.N + col] = (bf16)eluf(v + g.b_p1[col]);
        } else {
          int region = col >> 8, j = col & 255;
          float x = v + (region ? g.b_ps[j] : g.b_pm[j]);
          if (region) x = splusf(x);
          g.dout[(region ? OFF_PS : OFF_PL) + (long)row * ZZ + j] = x;
        }
      }
}

// dst[n*K + k] = bf16(src[(k + k_off)*ld + n]); grid (N/32, K/32), block (32,8)
__global__ void transpose_cvt(const float* __restrict__ src, bf16* __restrict__ dst,
                              int K, int N, int ld, int k_off) {
  __shared__ float tile[32][33];
  const int nb = blockIdx.x * 32, kb = blockIdx.y * 32;
  const int tx = threadIdx.x, ty = threadIdx.y;
#pragma unroll
  for (int j = 0; j < 32; j += 8)
    tile[ty + j][tx] = src[(long)(kb + ty + j + k_off) * ld + nb + tx];
  __syncthreads();
#pragma unroll
  for (int j = 0; j < 32; j += 8)
    dst[(long)(nb + ty + j) * K + kb + tx] = (bf16)tile[tx][ty + j];
}

__global__ void cvt_bf16(const float* __restrict__ src, bf16* __restrict__ dst, long n) {
  long i = ((long)blockIdx.x * blockDim.x + threadIdx.x) * 4;
  if (i < n) {
    float4 v = *(const float4*)(src + i);
    dst[i] = (bf16)v.x; dst[i + 1] = (bf16)v.y;
    dst[i + 2] = (bf16)v.z; dst[i + 3] = (bf16)v.w;
  }
}

__global__ void init_k(bf16* hbf, float* dout) {
  int i = blockIdx.x * 256 + threadIdx.x;
  hbf[i] = (bf16)0.f;
  dout[i] = 0.f;  // beliefs[0] = h0 = 0
}

extern "C" void kernel_launch(void* const* d_in, const int* in_sizes, int n_in,
                              void* d_out, int out_size, void* d_ws, size_t ws_size,
                              hipStream_t stream) {
  const float* obs  = (const float*)d_in[0];
  const float* act  = (const float*)d_in[1];
  const float* eps  = (const float*)d_in[2];
  const float* aggrW = (const float*)d_in[3];
  const float* aggrB = (const float*)d_in[4];
  const float* gWih = (const float*)d_in[5];
  const float* gWhh = (const float*)d_in[6];
  const float* gbih = (const float*)d_in[7];
  const float* gbhh = (const float*)d_in[8];
  const float* qW1  = (const float*)d_in[9];
  const float* qb1  = (const float*)d_in[10];
  const float* qWm  = (const float*)d_in[11];
  const float* qbm  = (const float*)d_in[12];
  const float* qWs  = (const float*)d_in[13];
  const float* qbs  = (const float*)d_in[14];
  const float* pW1  = (const float*)d_in[15];
  const float* pb1  = (const float*)d_in[16];
  const float* pWm  = (const float*)d_in[17];
  const float* pbm  = (const float*)d_in[18];
  const float* pWs  = (const float*)d_in[19];
  const float* pbs  = (const float*)d_in[20];
  float* dout = (float*)d_out;

  char* w = (char*)d_ws;
  size_t off = 0;
  auto alloc = [&](size_t bytes) -> char* {
    char* r = w + off;
    off = (off + bytes + 255) & ~(size_t)255;
    return r;
  };
  bf16* WT_qobs = (bf16*)alloc((size_t)XX * HH * 2);        // q_W1[:X]^T
  bf16* WT_h   = (bf16*)alloc((size_t)4096 * 1024 * 2);     // [qW1[X:] | Whh]^T
  bf16* WT_qh  = (bf16*)alloc((size_t)512 * 1024 * 2);      // [qWm | qWs]^T
  bf16* WT_ag  = (bf16*)alloc((size_t)1024 * 320 * 2);      // aggr_W^T
  bf16* WT_ih  = (bf16*)alloc((size_t)3072 * 1024 * 2);     // Wih^T
  bf16* WT_p1  = (bf16*)alloc((size_t)1024 * 1024 * 2);     // pW1^T
  bf16* WT_ph  = (bf16*)alloc((size_t)512 * 1024 * 2);      // [pWm | pWs]^T
  bf16* obs_pre = (bf16*)alloc((size_t)TT * BB * HH * 2);   // aliased by p_hid after loop
  bf16* p_hid  = obs_pre;
  bf16* act_bf = (bf16*)alloc((size_t)TT * BB * AA * 2);
  bf16* h_bf   = (bf16*)alloc((size_t)BB * HH * 2);
  bf16* hid_q  = (bf16*)alloc((size_t)BB * HH * 2);
  bf16* z_bf   = (bf16*)alloc((size_t)BB * ZZ * 2);
  bf16* a_buf  = (bf16*)alloc((size_t)BB * HH * 2);
  float* gh_f  = (float*)alloc((size_t)BB * 3 * HH * 4);
  unsigned* bar = (unsigned*)alloc(256);
  (void)ws_size; (void)in_sizes; (void)n_in; (void)out_size;

  hipMemsetAsync(bar, 0, 256, stream);

  dim3 tb(32, 8);
  transpose_cvt<<<dim3(32, 32), tb, 0, stream>>>(qW1, WT_qobs, 1024, 1024, 1024, 0);
  transpose_cvt<<<dim3(32, 32), tb, 0, stream>>>(qW1, WT_h, 1024, 1024, 1024, 1024);
  transpose_cvt<<<dim3(96, 32), tb, 0, stream>>>(gWhh, WT_h + 1024 * 1024, 1024, 3072, 3072, 0);
  transpose_cvt<<<dim3(8, 32), tb, 0, stream>>>(qWm, WT_qh, 1024, 256, 256, 0);
  transpose_cvt<<<dim3(8, 32), tb, 0, stream>>>(qWs, WT_qh + 256 * 1024, 1024, 256, 256, 0);
  transpose_cvt<<<dim3(32, 10), tb, 0, stream>>>(aggrW, WT_ag, 320, 1024, 1024, 0);
  transpose_cvt<<<dim3(96, 32), tb, 0, stream>>>(gWih, WT_ih, 1024, 3072, 3072, 0);
  transpose_cvt<<<dim3(32, 32), tb, 0, stream>>>(pW1, WT_p1, 1024, 1024, 1024, 0);
  transpose_cvt<<<dim3(8, 32), tb, 0, stream>>>(pWm, WT_ph, 1024, 256, 256, 0);
  transpose_cvt<<<dim3(8, 32), tb, 0, stream>>>(pWs, WT_ph + 256 * 1024, 1024, 256, 256, 0);
  cvt_bf16<<<TT * BB * AA / 4 / 256, 256, 0, stream>>>(act, act_bf, (long)TT * BB * AA);
  init_k<<<BB * HH / 256, 256, 0, stream>>>(h_bf, dout);

  {  // obs_pre = obs @ qW1[:X]  (fully parallel, M = T*B)
    GArgs a{};
    a.Af = obs; a.lda = XX; a.Bt = WT_qobs;
    a.M = TT * BB; a.N = HH; a.K = XX; a.out_bf = obs_pre;
    gemm_k<128, 128, 0, true><<<(TT * BB / 128) * (HH / 128), 256, 0, stream>>>(a);
  }

  {  // persistent scan over all 64 steps
    ScanArgs s{};
    s.WT_h = WT_h; s.WT_qh = WT_qh; s.WT_ag = WT_ag; s.WT_ih = WT_ih;
    s.obs_pre = obs_pre; s.act_bf = act_bf;
    s.h_bf = h_bf; s.hid_q = hid_q; s.z_bf = z_bf; s.a_buf = a_buf;
    s.gh = gh_f;
    s.b_q1 = qb1; s.b_ghh = gbhh; s.b_qm = qbm; s.b_qs = qbs;
    s.b_ag = aggrB; s.b_gih = gbih;
    s.eps = eps; s.dout = dout; s.bar = bar;
    scan_k<<<NBLK, NTHR, 0, stream>>>(s);
  }

  {  // p_hid = elu(beliefs[0:T*B] @ pW1 + b1)  (batched)
    GArgs a{};
    a.Af = dout; a.lda = HH; a.Bt = WT_p1;
    a.M = TT * BB; a.N = HH; a.K = HH; a.out_bf = p_hid; a.b_p1 = pb1;
    gemm_k<128, 128, 5, true><<<(TT * BB / 128) * (HH / 128), 256, 0, stream>>>(a);
  }
  {  // p-heads: p_hid @ [pWm|pWs] -> d_out
    GArgs a{};
    a.A = p_hid; a.lda = HH; a.Bt = WT_ph;
    a.M = TT * BB; a.N = 512; a.K = HH;
    a.b_pm = pbm; a.b_ps = pbs; a.dout = dout;
    gemm_k<128, 128, 6, false><<<(TT * BB / 128) * (512 / 128), 256, 0, stream>>>(a);
  }
}

// Round 4
// 12771.725 us; speedup vs baseline: 1.3568x; 1.3568x over previous
//
#include <hip/hip_runtime.h>
#include <hip/hip_bf16.h>
#include <stdint.h>

#define TT 64
#define BB 512
#define XX 1024
#define HH 1024
#define ZZ 256
#define AA 64

#define NBLK 256
#define NTHR 512

typedef __bf16 bf16;
typedef bf16 bf16x8 __attribute__((ext_vector_type(8)));
typedef float f32x4 __attribute__((ext_vector_type(4)));

// d_out layout (fp32): beliefs[T+1,B,H] | q_loc | q_scale | p_loc | p_scale | z_q (each [T,B,Z])
#define SZ_BEL ((long)(TT + 1) * BB * HH)
#define SZ_TBZ ((long)TT * BB * ZZ)
#define OFF_QL (SZ_BEL)
#define OFF_QS (OFF_QL + SZ_TBZ)
#define OFF_PL (OFF_QL + 2 * SZ_TBZ)
#define OFF_PS (OFF_QL + 3 * SZ_TBZ)
#define OFF_ZQ (OFF_QL + 4 * SZ_TBZ)

#define GLL16(g, l)                                                         \
  __builtin_amdgcn_global_load_lds(                                         \
      (__attribute__((address_space(1))) void*)(g),                         \
      (__attribute__((address_space(3))) void*)(l), 16, 0, 0)

#define MFMA(a, b, c) __builtin_amdgcn_mfma_f32_16x16x32_bf16(a, b, c, 0, 0, 0)

__device__ __forceinline__ float eluf(float x) { return x > 0.f ? x : expf(x) - 1.f; }
__device__ __forceinline__ float splusf(float x) { return fmaxf(x, 0.f) + log1pf(expf(-fabsf(x))); }
__device__ __forceinline__ float sigf(float x) { return 1.f / (1.f + expf(-x)); }

// ---------------- persistent scan kernel ----------------

struct ScanArgs {
  const bf16 *WT_q1h, *WT_hh, *WT_qh, *WT_ag, *WT_ih;
  const bf16 *obs_pre, *act_bf;
  bf16 *hA, *hB, *hid_q, *z_bf, *a_buf;
  const float *b_q1, *b_ghh, *b_qm, *b_qs, *b_ag, *b_gih;
  const float* eps;
  float* dout;
  unsigned* bar;  // [16*32] leaves + root at +512
};

// Two-level tree barrier: 16 leaves (one 128B line each, 16 adders) -> root.
// All 256 blocks co-resident by construction (48KB LDS, 512thr, grid=256).
__device__ __forceinline__ void gsync(unsigned* bar, unsigned& gen) {
  __syncthreads();
  ++gen;
  if (threadIdx.x == 0) {
    __threadfence();
    const int bid = blockIdx.x;
    unsigned* lf = bar + (bid >> 4) * 32;
    unsigned* root = bar + 512;
    atomicAdd(lf, 1u);
    if ((bid & 15) == 0) {
      while (__hip_atomic_load(lf, __ATOMIC_RELAXED, __HIP_MEMORY_SCOPE_AGENT) < 16u * gen)
        __builtin_amdgcn_s_sleep(1);
      atomicAdd(root, 1u);
    }
    while (__hip_atomic_load(root, __ATOMIC_RELAXED, __HIP_MEMORY_SCOPE_AGENT) < 16u * gen)
      __builtin_amdgcn_s_sleep(1);
  }
  __syncthreads();
  __threadfence();
}

// swizzled frag read: w = byte offset within 128-byte k-row (16B aligned)
__device__ __forceinline__ bf16x8 ldfrag(const char* buf, int row, int w) {
  return *(const bf16x8*)(buf + row * 128 + (w ^ ((row & 7) << 4)));
}

// stage nrows x 64 bf16 k-tile, linear LDS dest, inverse-swizzled global source
__device__ __forceinline__ void stage_rows(const bf16* base, long ld, int k0,
                                           char* lds, int nrows) {
  for (int c = threadIdx.x; c < nrows * 8; c += NTHR) {
    int row = c >> 3, cb = (c & 7) << 4;
    int scb = (cb ^ ((row & 7) << 4)) >> 1;
    GLL16(base + (long)row * ld + k0 + scb, lds + c * 16);
  }
}

__global__ __launch_bounds__(NTHR, 2) void scan_k(ScanArgs s) {
  __shared__ char smem[49152];
  const int bid = blockIdx.x, tid = threadIdx.x;
  const int wid = tid >> 6, lane = tid & 63;
  const int lr = lane & 15, lk = lane >> 4;
  unsigned gen = 0;

  const int m0 = (bid >> 5) * 64;        // 8 m-groups of 64 rows (P1/P2/P3/P4)
  const int npart = bid & 31;            // 32 n-partitions
  const int wmf = wid & 3, wnf = wid >> 2;  // 4 m-waves x 2 n-waves

  for (int t = 0; t < TT; ++t) {
    const bf16* hc = (t & 1) ? s.hB : s.hA;
    bf16* hn = (t & 1) ? s.hA : s.hB;

    // ---- P1: hid_q = elu(h@Wq1h + obs_pre + b)  M=512,N=1024,K=1024
    // tile 64x32, dbuf BK=64, 16 kts. bufs: {A 8K + B 4K} x2 @ 0 / 12K
    {
      const int j0 = npart * 32;
      const bf16* Ag = hc + (long)m0 * HH;
      const bf16* Bg = s.WT_q1h + (long)j0 * HH;
      f32x4 acc = {};
      stage_rows(Ag, HH, 0, smem, 64);
      stage_rows(Bg, HH, 0, smem + 8192, 32);
      __syncthreads();
      for (int kt = 0; kt < 16; ++kt) {
        char* bc = smem + (kt & 1) * 12288;
        char* bn = smem + ((kt & 1) ^ 1) * 12288;
        if (kt < 15) {
          stage_rows(Ag, HH, (kt + 1) * 64, bn, 64);
          stage_rows(Bg, HH, (kt + 1) * 64, bn + 8192, 32);
        }
#pragma unroll
        for (int ks = 0; ks < 2; ++ks) {
          int w = ks * 64 + lk * 16;
          bf16x8 a = ldfrag(bc, wmf * 16 + lr, w);
          bf16x8 b = ldfrag(bc + 8192, wnf * 16 + lr, w);
          acc = MFMA(a, b, acc);
        }
        __syncthreads();
      }
#pragma unroll
      for (int r = 0; r < 4; ++r) {
        int row = m0 + wmf * 16 + lk * 4 + r;
        int col = j0 + wnf * 16 + lr;
        float x = acc[r] + s.b_q1[col] + (float)s.obs_pre[((long)t * BB + row) * HH + col];
        s.hid_q[row * HH + col] = (bf16)eluf(x);
      }
    }
    gsync(s.bar, gen);

    // ---- P2: q-dual heads + rsample  M=512, j=256, K=1024. 128 active blocks
    // tile 64 rows x 16 j (dual loc/scale). waves 0..3 compute.
    if (npart < 16) {
      const int j0 = npart * 16;
      const bf16* Ag = s.hid_q + (long)m0 * HH;
      f32x4 accL = {}, accS = {};
      stage_rows(Ag, HH, 0, smem, 64);
      for (int c = tid; c < 256; c += NTHR) {
        int rr = c >> 3, cb = (c & 7) << 4;
        int scb = (cb ^ ((rr & 7) << 4)) >> 1;
        int src = (rr < 16) ? (j0 + rr) : (256 + j0 + rr - 16);
        GLL16(s.WT_qh + (long)src * HH + scb, smem + 8192 + c * 16);
      }
      __syncthreads();
      for (int kt = 0; kt < 16; ++kt) {
        char* bc = smem + (kt & 1) * 12288;
        char* bn = smem + ((kt & 1) ^ 1) * 12288;
        if (kt < 15) {
          stage_rows(Ag, HH, (kt + 1) * 64, bn, 64);
          for (int c = tid; c < 256; c += NTHR) {
            int rr = c >> 3, cb = (c & 7) << 4;
            int scb = (cb ^ ((rr & 7) << 4)) >> 1;
            int src = (rr < 16) ? (j0 + rr) : (256 + j0 + rr - 16);
            GLL16(s.WT_qh + (long)src * HH + (kt + 1) * 64 + scb, bn + 8192 + c * 16);
          }
        }
        if (wid < 4) {
#pragma unroll
          for (int ks = 0; ks < 2; ++ks) {
            int w = ks * 64 + lk * 16;
            bf16x8 a = ldfrag(bc, wid * 16 + lr, w);
            bf16x8 bl = ldfrag(bc + 8192, lr, w);
            bf16x8 bs = ldfrag(bc + 8192, 16 + lr, w);
            accL = MFMA(a, bl, accL);
            accS = MFMA(a, bs, accS);
          }
        }
        __syncthreads();
      }
      if (wid < 4) {
#pragma unroll
        for (int r = 0; r < 4; ++r) {
          int row = m0 + wid * 16 + lk * 4 + r;
          int j = j0 + lr;
          long o = ((long)t * BB + row) * ZZ + j;
          float loc = accL[r] + s.b_qm[j];
          float sc = splusf(accS[r] + s.b_qs[j]);
          float z = loc + sc * s.eps[o];
          s.dout[OFF_QL + o] = loc;
          s.dout[OFF_QS + o] = sc;
          s.dout[OFF_ZQ + o] = z;
          s.z_bf[row * ZZ + j] = (bf16)z;
        }
      }
    }
    gsync(s.bar, gen);

    // ---- P3: a = elu([z|act]@aggrW + b)  M=512,N=1024,K=320. tile 64x32, 5 kts
    {
      const int j0 = npart * 32;
      const bf16* Bg = s.WT_ag + (long)j0 * 320;
      f32x4 acc = {};
      stage_rows(s.z_bf + (long)m0 * ZZ, ZZ, 0, smem, 64);
      stage_rows(Bg, 320, 0, smem + 8192, 32);
      __syncthreads();
      for (int kt = 0; kt < 5; ++kt) {
        char* bc = smem + (kt & 1) * 12288;
        char* bn = smem + ((kt & 1) ^ 1) * 12288;
        if (kt < 4) {
          if (kt < 3)
            stage_rows(s.z_bf + (long)m0 * ZZ, ZZ, (kt + 1) * 64, bn, 64);
          else
            stage_rows(s.act_bf + (long)t * BB * AA + (long)m0 * AA, AA, 0, bn, 64);
          stage_rows(Bg, 320, (kt + 1) * 64, bn + 8192, 32);
        }
#pragma unroll
        for (int ks = 0; ks < 2; ++ks) {
          int w = ks * 64 + lk * 16;
          bf16x8 a = ldfrag(bc, wmf * 16 + lr, w);
          bf16x8 b = ldfrag(bc + 8192, wnf * 16 + lr, w);
          acc = MFMA(a, b, acc);
        }
        __syncthreads();
      }
#pragma unroll
      for (int r = 0; r < 4; ++r) {
        int row = m0 + wmf * 16 + lk * 4 + r;
        int col = j0 + wnf * 16 + lr;
        s.a_buf[row * HH + col] = (bf16)eluf(acc[r] + s.b_ag[col]);
      }
    }
    gsync(s.bar, gen);

    // ---- P4: gi = a@Wih, gh = h@Whh (N=3072 each) + GRU gates -> h_new
    // tile 64 rows x 32 j x 3 gates x 2 mats. single-buffer BK=64, 16 kts.
    // LDS: Aa@0(8K) Ah@8K Bih@16K(12K) Bhh@28K(12K)
    {
      const int j0 = npart * 32;
      const bf16* Aa = s.a_buf + (long)m0 * HH;
      const bf16* Ah = hc + (long)m0 * HH;
      f32x4 gi[3] = {}, gh[3] = {};
      for (int kt = 0; kt < 16; ++kt) {
        int k0 = kt * 64;
        stage_rows(Aa, HH, k0, smem, 64);
        stage_rows(Ah, HH, k0, smem + 8192, 64);
#pragma unroll
        for (int g = 0; g < 3; ++g) {
          stage_rows(s.WT_ih + (long)(g * HH + j0) * HH, HH, k0, smem + 16384 + g * 4096, 32);
          stage_rows(s.WT_hh + (long)(g * HH + j0) * HH, HH, k0, smem + 28672 + g * 4096, 32);
        }
        __syncthreads();
#pragma unroll
        for (int ks = 0; ks < 2; ++ks) {
          int w = ks * 64 + lk * 16;
          bf16x8 aa = ldfrag(smem, wmf * 16 + lr, w);
          bf16x8 ah = ldfrag(smem + 8192, wmf * 16 + lr, w);
#pragma unroll
          for (int g = 0; g < 3; ++g) {
            bf16x8 bi = ldfrag(smem + 16384, g * 32 + wnf * 16 + lr, w);
            bf16x8 bh = ldfrag(smem + 28672, g * 32 + wnf * 16 + lr, w);
            gi[g] = MFMA(aa, bi, gi[g]);
            gh[g] = MFMA(ah, bh, gh[g]);
          }
        }
        __syncthreads();
      }
#pragma unroll
      for (int r = 0; r < 4; ++r) {
        int row = m0 + wmf * 16 + lk * 4 + r;
        int j = j0 + wnf * 16 + lr;
        float ir = gi[0][r] + s.b_gih[j] + gh[0][r] + s.b_ghh[j];
        float iz = gi[1][r] + s.b_gih[HH + j] + gh[1][r] + s.b_ghh[HH + j];
        float hn_pre = gh[2][r] + s.b_ghh[2 * HH + j];
        float in_pre = gi[2][r] + s.b_gih[2 * HH + j];
        float rr = sigf(ir);
        float zz = sigf(iz);
        float nn = tanhf(in_pre + rr * hn_pre);
        float h = (float)hc[row * HH + j];
        float hnew = (1.f - zz) * nn + zz * h;
        hn[row * HH + j] = (bf16)hnew;
        s.dout[(long)(t + 1) * BB * HH + (long)row * HH + j] = hnew;
      }
    }
    gsync(s.bar, gen);
  }
}

// ---------------- batched GEMMs (prep / tails) ----------------

struct GArgs {
  const bf16* A; const float* Af;
  long lda;
  const bf16* Bt;
  int M, N, K;
  const float *b_p1, *b_pm, *b_ps;
  bf16* out_bf;
  float* dout;
};

// EPI: 0 = store bf16 raw   5 = elu+bias -> bf16   6 = p-heads -> d_out
template <int BM, int BN, int EPI, bool AF32>
__global__ __launch_bounds__(256) void gemm_k(GArgs g) {
  constexpr int BK = 32;
  constexpr int WTM = BM / 2, WTN = BN / 2;
  constexpr int MR = WTM / 16, NR = WTN / 16;
  constexpr int CA = BM * 4 / 256, CB = BN * 4 / 256;
  __shared__ bf16 sA[BM * BK];
  __shared__ bf16 sB[BN * BK];
  const int nbm = g.M / BM;
  const int bm = blockIdx.x % nbm, bn = blockIdx.x / nbm;
  const int m0 = bm * BM, n0 = bn * BN;
  const int tid = threadIdx.x;
  const int wid = tid >> 6, lane = tid & 63;
  const int wm = wid & 1, wn = wid >> 1;
  const int lr = lane & 15, lk = lane >> 4;

  f32x4 acc[MR][NR] = {};

  for (int k0 = 0; k0 < g.K; k0 += BK) {
    __syncthreads();
    if constexpr (AF32) {
#pragma unroll
      for (int i = 0; i < CA; i++) {
        int c = tid + i * 256, row = c >> 2, kc = c & 3;
        const float* sp = g.Af + (long)(m0 + row) * g.lda + k0 + kc * 8;
        float4 v0 = *(const float4*)sp;
        float4 v1 = *(const float4*)(sp + 4);
        bf16x8 p;
        p[0] = (bf16)v0.x; p[1] = (bf16)v0.y; p[2] = (bf16)v0.z; p[3] = (bf16)v0.w;
        p[4] = (bf16)v1.x; p[5] = (bf16)v1.y; p[6] = (bf16)v1.z; p[7] = (bf16)v1.w;
        *(bf16x8*)&sA[c * 8] = p;
      }
    } else {
#pragma unroll
      for (int i = 0; i < CA; i++) {
        int c = tid + i * 256, row = c >> 2, kc = c & 3;
        GLL16(g.A + (long)(m0 + row) * g.lda + k0 + kc * 8, &sA[c * 8]);
      }
    }
#pragma unroll
    for (int i = 0; i < CB; i++) {
      int c = tid + i * 256, row = c >> 2, kc = c & 3;
      GLL16(g.Bt + (long)(n0 + row) * g.K + k0 + kc * 8, &sB[c * 8]);
    }
    __syncthreads();
    bf16x8 af[MR];
#pragma unroll
    for (int mi = 0; mi < MR; mi++)
      af[mi] = *(const bf16x8*)&sA[(wm * WTM + mi * 16 + lr) * BK + lk * 8];
#pragma unroll
    for (int nj = 0; nj < NR; nj++) {
      bf16x8 bfr = *(const bf16x8*)&sB[(wn * WTN + nj * 16 + lr) * BK + lk * 8];
#pragma unroll
      for (int mi = 0; mi < MR; mi++)
        acc[mi][nj] = MFMA(af[mi], bfr, acc[mi][nj]);
    }
  }

#pragma unroll
  for (int mi = 0; mi < MR; mi++)
#pragma unroll
    for (int nj = 0; nj < NR; nj++)
#pragma unroll
      for (int r = 0; r < 4; r++) {
        const int row = m0 + wm * WTM + mi * 16 + lk * 4 + r;
        const int col = n0 + wn * WTN + nj * 16 + lr;
        float v = acc[mi][nj][r];
        if constexpr (EPI == 0) {
          g.out_bf[(long)row * g.N + col] = (bf16)v;
        } else if constexpr (EPI == 5) {
          g.out_bf[(long)row * g.N + col] = (bf16)eluf(v + g.b_p1[col]);
        } else {
          int region = col >> 8, j = col & 255;
          float x = v + (region ? g.b_ps[j] : g.b_pm[j]);
          if (region) x = splusf(x);
          g.dout[(region ? OFF_PS : OFF_PL) + (long)row * ZZ + j] = x;
        }
      }
}

// dst[n*K + k] = bf16(src[(k + k_off)*ld + n]); grid (N/32, K/32), block (32,8)
__global__ void transpose_cvt(const float* __restrict__ src, bf16* __restrict__ dst,
                              int K, int N, int ld, int k_off) {
  __shared__ float tile[32][33];
  const int nb = blockIdx.x * 32, kb = blockIdx.y * 32;
  const int tx = threadIdx.x, ty = threadIdx.y;
#pragma unroll
  for (int j = 0; j < 32; j += 8)
    tile[ty + j][tx] = src[(long)(kb + ty + j + k_off) * ld + nb + tx];
  __syncthreads();
#pragma unroll
  for (int j = 0; j < 32; j += 8)
    dst[(long)(nb + ty + j) * K + kb + tx] = (bf16)tile[tx][ty + j];
}

__global__ void cvt_bf16(const float* __restrict__ src, bf16* __restrict__ dst, long n) {
  long i = ((long)blockIdx.x * blockDim.x + threadIdx.x) * 4;
  if (i < n) {
    float4 v = *(const float4*)(src + i);
    dst[i] = (bf16)v.x; dst[i + 1] = (bf16)v.y;
    dst[i + 2] = (bf16)v.z; dst[i + 3] = (bf16)v.w;
  }
}

__global__ void init_k(bf16* hA, float* dout) {
  int i = blockIdx.x * 256 + threadIdx.x;
  hA[i] = (bf16)0.f;
  dout[i] = 0.f;  // beliefs[0] = h0 = 0
}

extern "C" void kernel_launch(void* const* d_in, const int* in_sizes, int n_in,
                              void* d_out, int out_size, void* d_ws, size_t ws_size,
                              hipStream_t stream) {
  const float* obs  = (const float*)d_in[0];
  const float* act  = (const float*)d_in[1];
  const float* eps  = (const float*)d_in[2];
  const float* aggrW = (const float*)d_in[3];
  const float* aggrB = (const float*)d_in[4];
  const float* gWih = (const float*)d_in[5];
  const float* gWhh = (const float*)d_in[6];
  const float* gbih = (const float*)d_in[7];
  const float* gbhh = (const float*)d_in[8];
  const float* qW1  = (const float*)d_in[9];
  const float* qb1  = (const float*)d_in[10];
  const float* qWm  = (const float*)d_in[11];
  const float* qbm  = (const float*)d_in[12];
  const float* qWs  = (const float*)d_in[13];
  const float* qbs  = (const float*)d_in[14];
  const float* pW1  = (const float*)d_in[15];
  const float* pb1  = (const float*)d_in[16];
  const float* pWm  = (const float*)d_in[17];
  const float* pbm  = (const float*)d_in[18];
  const float* pWs  = (const float*)d_in[19];
  const float* pbs  = (const float*)d_in[20];
  float* dout = (float*)d_out;

  char* w = (char*)d_ws;
  size_t off = 0;
  auto alloc = [&](size_t bytes) -> char* {
    char* r = w + off;
    off = (off + bytes + 255) & ~(size_t)255;
    return r;
  };
  bf16* WT_qobs = (bf16*)alloc((size_t)XX * HH * 2);        // q_W1[:X]^T
  bf16* WT_q1h = (bf16*)alloc((size_t)HH * HH * 2);         // q_W1[X:]^T
  bf16* WT_hh  = (bf16*)alloc((size_t)3072 * HH * 2);       // Whh^T
  bf16* WT_qh  = (bf16*)alloc((size_t)512 * HH * 2);        // [qWm | qWs]^T
  bf16* WT_ag  = (bf16*)alloc((size_t)1024 * 320 * 2);      // aggr_W^T
  bf16* WT_ih  = (bf16*)alloc((size_t)3072 * HH * 2);       // Wih^T
  bf16* WT_p1  = (bf16*)alloc((size_t)HH * HH * 2);         // pW1^T
  bf16* WT_ph  = (bf16*)alloc((size_t)512 * HH * 2);        // [pWm | pWs]^T
  bf16* obs_pre = (bf16*)alloc((size_t)TT * BB * HH * 2);   // aliased by p_hid after scan
  bf16* p_hid  = obs_pre;
  bf16* act_bf = (bf16*)alloc((size_t)TT * BB * AA * 2);
  bf16* hA     = (bf16*)alloc((size_t)BB * HH * 2);
  bf16* hB     = (bf16*)alloc((size_t)BB * HH * 2);
  bf16* hid_q  = (bf16*)alloc((size_t)BB * HH * 2);
  bf16* z_bf   = (bf16*)alloc((size_t)BB * ZZ * 2);
  bf16* a_buf  = (bf16*)alloc((size_t)BB * HH * 2);
  unsigned* bar = (unsigned*)alloc(4096);
  (void)ws_size; (void)in_sizes; (void)n_in; (void)out_size;

  hipMemsetAsync(bar, 0, 4096, stream);

  dim3 tb(32, 8);
  transpose_cvt<<<dim3(32, 32), tb, 0, stream>>>(qW1, WT_qobs, 1024, 1024, 1024, 0);
  transpose_cvt<<<dim3(32, 32), tb, 0, stream>>>(qW1, WT_q1h, 1024, 1024, 1024, 1024);
  transpose_cvt<<<dim3(96, 32), tb, 0, stream>>>(gWhh, WT_hh, 1024, 3072, 3072, 0);
  transpose_cvt<<<dim3(8, 32), tb, 0, stream>>>(qWm, WT_qh, 1024, 256, 256, 0);
  transpose_cvt<<<dim3(8, 32), tb, 0, stream>>>(qWs, WT_qh + 256 * 1024, 1024, 256, 256, 0);
  transpose_cvt<<<dim3(32, 10), tb, 0, stream>>>(aggrW, WT_ag, 320, 1024, 1024, 0);
  transpose_cvt<<<dim3(96, 32), tb, 0, stream>>>(gWih, WT_ih, 1024, 3072, 3072, 0);
  transpose_cvt<<<dim3(32, 32), tb, 0, stream>>>(pW1, WT_p1, 1024, 1024, 1024, 0);
  transpose_cvt<<<dim3(8, 32), tb, 0, stream>>>(pWm, WT_ph, 1024, 256, 256, 0);
  transpose_cvt<<<dim3(8, 32), tb, 0, stream>>>(pWs, WT_ph + 256 * 1024, 1024, 256, 256, 0);
  cvt_bf16<<<TT * BB * AA / 4 / 256, 256, 0, stream>>>(act, act_bf, (long)TT * BB * AA);
  init_k<<<BB * HH / 256, 256, 0, stream>>>(hA, dout);

  {  // obs_pre = obs @ qW1[:X]  (fully parallel, M = T*B)
    GArgs a{};
    a.Af = obs; a.lda = XX; a.Bt = WT_qobs;
    a.M = TT * BB; a.N = HH; a.K = XX; a.out_bf = obs_pre;
    gemm_k<128, 128, 0, true><<<(TT * BB / 128) * (HH / 128), 256, 0, stream>>>(a);
  }

  {  // persistent scan over all 64 steps
    ScanArgs s{};
    s.WT_q1h = WT_q1h; s.WT_hh = WT_hh; s.WT_qh = WT_qh;
    s.WT_ag = WT_ag; s.WT_ih = WT_ih;
    s.obs_pre = obs_pre; s.act_bf = act_bf;
    s.hA = hA; s.hB = hB; s.hid_q = hid_q; s.z_bf = z_bf; s.a_buf = a_buf;
    s.b_q1 = qb1; s.b_ghh = gbhh; s.b_qm = qbm; s.b_qs = qbs;
    s.b_ag = aggrB; s.b_gih = gbih;
    s.eps = eps; s.dout = dout; s.bar = bar;
    scan_k<<<NBLK, NTHR, 0, stream>>>(s);
  }

  {  // p_hid = elu(beliefs[0:T*B] @ pW1 + b1)  (batched)
    GArgs a{};
    a.Af = dout; a.lda = HH; a.Bt = WT_p1;
    a.M = TT * BB; a.N = HH; a.K = HH; a.out_bf = p_hid; a.b_p1 = pb1;
    gemm_k<128, 128, 5, true><<<(TT * BB / 128) * (HH / 128), 256, 0, stream>>>(a);
  }
  {  // p-heads: p_hid @ [pWm|pWs] -> d_out
    GArgs a{};
    a.A = p_hid; a.lda = HH; a.Bt = WT_ph;
    a.M = TT * BB; a.N = 512; a.K = HH;
    a.b_pm = pbm; a.b_ps = pbs; a.dout = dout;
    gemm_k<128, 128, 6, false><<<(TT * BB / 128) * (512 / 128), 256, 0, stream>>>(a);
  }
}